// Round 4
// baseline (444.066 us; speedup 1.0000x reference)
//
#include <hip/hip_runtime.h>
#include <math.h>

#define NPIX   131072      // 8*128*128
#define CCH    256
#define HW     16384       // 128*128
#define BSTR   4194304     // 256*16384 (features b-stride; == 16*262144 for outputs_old)
#define NUMC   21
#define KC     5376        // 21*256
#define NREP   8
#define TP     17          // tile pad: bank = (17*l + j) % 32 -> all distinct per wave

// ---------------- kernel 1: pseudo labels + per-class counts ----------------
__global__ __launch_bounds__(256) void k_labels(const int* __restrict__ labels,
                                                const float* __restrict__ outputs_old,
                                                int* __restrict__ lab,
                                                float* __restrict__ gcnt)
{
    __shared__ float cnt[NUMC];
    if (threadIdx.x < NUMC) cnt[threadIdx.x] = 0.f;
    __syncthreads();

    int p = blockIdx.x * 256 + threadIdx.x;
    int b = p >> 14;
    int rem = p & 16383;
    int h = rem >> 7;
    int w = rem & 127;
    int ld = labels[b * 262144 + (h * 4) * 512 + (w * 4)];
    int out = ld;
    if (ld == 0) {
        const float* oo = outputs_old + (size_t)b * BSTR + (size_t)(h * 4) * 512 + (w * 4);
        float v0 = oo[0];
        float best = (v0 < 0.7f) ? 0.0f : v0;
        int bi = 0;
        #pragma unroll
        for (int c = 1; c < 16; ++c) {
            float v = oo[(size_t)c * 262144];
            v = (v < 0.7f) ? 0.0f : v;
            if (v > best) { best = v; bi = c; }   // strict > == first-occurrence argmax
        }
        out = bi;
    }
    lab[p] = out;
    unsafeAtomicAdd(&cnt[out], 1.0f);   // one collision-prone atomic per thread: negligible
    __syncthreads();
    if (threadIdx.x < NUMC) unsafeAtomicAdd(&gcnt[threadIdx.x], cnt[threadIdx.x]);
}

// ---------------- kernel 2: fused norm + per-class accumulate ----------------
// 512 blocks x 256 threads; block owns 256 contiguous pixels (16 chunks of 16).
// thread <-> channel. All LDS atomics have per-wave-distinct addresses -> no
// same-address serialization (the R1-R3 344us pathology).
__global__ __launch_bounds__(256, 2) void k_main(const float* __restrict__ fa,
                                                 const float* __restrict__ fo,
                                                 const int* __restrict__ lab,
                                                 float* __restrict__ partA,
                                                 float* __restrict__ partO)
{
    __shared__ float tile[CCH * TP];     // [256 ch][16 px] padded
    __shared__ float accA[KC];
    __shared__ float accO[KC];
    __shared__ float invn[16];
    __shared__ int   kl[16];

    const int t = threadIdx.x;
    const int w = t >> 6, l = t & 63;
    for (int i = t; i < KC; i += 256) { accA[i] = 0.f; accO[i] = 0.f; }

    const int pbase = blockIdx.x * 256;
    const int b   = pbase >> 14;
    const int hw0 = pbase & 16383;
    const float* gA = fa + (size_t)b * BSTR + hw0;
    const float* gO = fo + (size_t)b * BSTR + hw0;

    // staging map: thread t loads 8 float2: channel sc+32*i, pixels sj..sj+1
    const int sc = t >> 3;
    const int sj = (t & 7) * 2;

    float2 vb[8];   // prefetch buffer (statically indexed via full unroll)
    // prologue: prefetch A-tile of chunk 0
    #pragma unroll
    for (int i = 0; i < 8; ++i)
        vb[i] = *(const float2*)(gA + (size_t)(sc + 32 * i) * HW + sj);

    for (int chunk = 0; chunk < 16; ++chunk) {
        const int j0 = chunk * 16;

        // ---------- tensor A ----------
        __syncthreads();                           // tile free (prev chunk done)
        if (t < 16) kl[t] = lab[pbase + j0 + t];
        #pragma unroll
        for (int i = 0; i < 8; ++i) {
            int c = sc + 32 * i;
            tile[c * TP + sj]     = vb[i].x;
            tile[c * TP + sj + 1] = vb[i].y;
        }
        // issue O-tile loads; latency hides under sumsq+acc below
        #pragma unroll
        for (int i = 0; i < 8; ++i)
            vb[i] = *(const float2*)(gO + (size_t)(sc + 32 * i) * HW + j0 + sj);
        __syncthreads();                           // tile + kl ready
        #pragma unroll
        for (int q = 0; q < 4; ++q) {              // wave w owns pixels w*4+q
            int j = w * 4 + q;
            float s = 0.f;
            #pragma unroll
            for (int m = 0; m < 4; ++m) { float v = tile[(l + m * 64) * TP + j]; s += v * v; }
            #pragma unroll
            for (int off = 32; off > 0; off >>= 1) s += __shfl_xor(s, off, 64);
            if (l == 0) invn[j] = 1.0f / fmaxf(sqrtf(s), 1e-12f);
        }
        __syncthreads();                           // invn ready
        #pragma unroll
        for (int j = 0; j < 16; ++j) {
            float v = tile[t * TP + j];
            unsafeAtomicAdd(&accA[kl[j] * 256 + t], v * invn[j]);  // addr distinct per lane
        }

        // ---------- tensor O ----------
        __syncthreads();                           // acc-A done reading tile/invn
        #pragma unroll
        for (int i = 0; i < 8; ++i) {
            int c = sc + 32 * i;
            tile[c * TP + sj]     = vb[i].x;
            tile[c * TP + sj + 1] = vb[i].y;
        }
        // prefetch next chunk's A-tile
        if (chunk < 15) {
            #pragma unroll
            for (int i = 0; i < 8; ++i)
                vb[i] = *(const float2*)(gA + (size_t)(sc + 32 * i) * HW + j0 + 16 + sj);
        }
        __syncthreads();                           // tile ready
        #pragma unroll
        for (int q = 0; q < 4; ++q) {
            int j = w * 4 + q;
            float s = 0.f;
            #pragma unroll
            for (int m = 0; m < 4; ++m) { float v = tile[(l + m * 64) * TP + j]; s += v * v; }
            #pragma unroll
            for (int off = 32; off > 0; off >>= 1) s += __shfl_xor(s, off, 64);
            if (l == 0) invn[j] = 1.0f / fmaxf(sqrtf(s), 1e-12f);
        }
        __syncthreads();                           // invn ready
        #pragma unroll
        for (int j = 0; j < 16; ++j) {
            float v = tile[t * TP + j];
            unsafeAtomicAdd(&accO[kl[j] * 256 + t], v * invn[j]);
        }
    }

    __syncthreads();
    const int rep = blockIdx.x & (NREP - 1);       // 8 replicas -> contention 64/addr
    for (int i = t; i < KC; i += 256) {
        unsafeAtomicAdd(&partA[rep * KC + i], accA[i]);
        unsafeAtomicAdd(&partO[rep * KC + i], accO[i]);
    }
}

// ---------------- kernel 3: finalize (tiny) ----------------
__global__ __launch_bounds__(256) void k_final(const float* __restrict__ partA,
                                               const float* __restrict__ partO,
                                               const float* __restrict__ gcnt,
                                               float* __restrict__ out)
{
    __shared__ float anc[NUMC * 260];
    __shared__ float con[NUMC * 260];
    __shared__ float adc[NUMC * 44];
    __shared__ float cntS[NUMC];
    __shared__ float rowloss[NUMC];
    __shared__ float rowvalid[NUMC];

    if (threadIdx.x < NUMC) cntS[threadIdx.x] = gcnt[threadIdx.x];
    __syncthreads();
    for (int i = threadIdx.x; i < KC; i += 256) {
        float sA = 0.f, sO = 0.f;
        #pragma unroll
        for (int r = 0; r < NREP; ++r) { sA += partA[r * KC + i]; sO += partO[r * KC + i]; }
        int k = i >> 8, c = i & 255;
        float cn = cntS[k];
        bool pr = cn > 0.f;
        float d = pr ? cn : 1.f;
        anc[k * 260 + c] = pr ? sA / d : 0.f;
        con[k * 260 + c] = pr ? sO / d : 0.f;
    }
    __syncthreads();
    // adc[k][j] = dot(anc_k, contrast_j)/T,  contrast = [anc; con]
    for (int pair = threadIdx.x; pair < NUMC * 2 * NUMC; pair += 256) {
        int k = pair / (2 * NUMC);
        int j = pair % (2 * NUMC);
        const float* ar = anc + k * 260;
        const float* br = (j < NUMC) ? (anc + j * 260) : (con + (j - NUMC) * 260);
        float s = 0.f;
        for (int c = 0; c < CCH; c += 4) {
            float4 a4 = *(const float4*)(ar + c);
            float4 b4 = *(const float4*)(br + c);
            s += a4.x * b4.x + a4.y * b4.y + a4.z * b4.z + a4.w * b4.w;
        }
        adc[k * 44 + j] = s / 0.07f;
    }
    __syncthreads();
    if (threadIdx.x < NUMC) {
        int k = threadIdx.x;
        bool pr = cntS[k] > 0.f;
        float neg = 0.f;       // faithful to source — negatives use UNshifted logits
        float mx = -1e30f;
        for (int j = 0; j < 2 * NUMC; ++j) {
            int cj = (j < NUMC) ? j : (j - NUMC);
            bool cp = cntS[cj] > 0.f;
            float v = adc[k * 44 + j];
            if (cp) {
                if (v > mx) mx = v;
                if (j != k && j != NUMC + k) neg += expf(v);
            }
        }
        float sh = adc[k * 44 + NUMC + k] - mx;
        float rl = -(sh - logf(expf(sh) + neg));
        rowloss[k] = pr ? rl : 0.f;
        rowvalid[k] = pr ? 1.f : 0.f;
    }
    __syncthreads();
    if (threadIdx.x == 0) {
        float s = 0.f, v = 0.f;
        for (int kk = 0; kk < NUMC; ++kk) { s += rowloss[kk]; v += rowvalid[kk]; }
        out[0] = s / fmaxf(v, 1.f);
    }
}

// ---------------- launch ----------------
extern "C" void kernel_launch(void* const* d_in, const int* in_sizes, int n_in,
                              void* d_out, int out_size, void* d_ws, size_t ws_size,
                              hipStream_t stream) {
    const int*   labels      = (const int*)  d_in[0];
    const float* feats_old   = (const float*)d_in[1];
    const float* feats       = (const float*)d_in[2];
    const float* outputs_old = (const float*)d_in[3];
    // d_in[4] (outputs) and d_in[5] (prototypes) are unused by the reference math.

    float* ws    = (float*)d_ws;
    int*   lab   = (int*)ws;                       // [131072]
    float* partA = ws + 131072;                    // [8*5376]
    float* partO = partA + NREP * KC;              // [8*5376]
    float* gcnt  = partO + NREP * KC;              // [21]

    hipMemsetAsync(partA, 0, (size_t)(2 * NREP * KC + NUMC) * sizeof(float), stream);

    k_labels<<<NPIX / 256, 256, 0, stream>>>(labels, outputs_old, lab, gcnt);
    k_main  <<<NPIX / 256, 256, 0, stream>>>(feats, feats_old, lab, partA, partO);
    k_final <<<1, 256, 0, stream>>>(partA, partO, gcnt, (float*)d_out);
}

// Round 5
// 399.147 us; speedup vs baseline: 1.1125x; 1.1125x over previous
//
#include <hip/hip_runtime.h>
#include <math.h>

#define NPIX   131072      // 8*128*128
#define CCH    256
#define HW     16384       // 128*128
#define BSTR   4194304     // 256*16384 (features b-stride)
#define NUMC   21
#define KC     5376        // 21*256
#define NREP   16
#define TPAD   257         // [32 px][257 ch] tile: reads conflict-free, writes ~2-way

// acc[] indexed ONLY by compile-time constants -> stays in VGPRs (rule #20)
#define ACC21(arr, kk, xx) do { switch (kk) { \
    case 0:  arr[0]  += (xx); break; case 1:  arr[1]  += (xx); break; \
    case 2:  arr[2]  += (xx); break; case 3:  arr[3]  += (xx); break; \
    case 4:  arr[4]  += (xx); break; case 5:  arr[5]  += (xx); break; \
    case 6:  arr[6]  += (xx); break; case 7:  arr[7]  += (xx); break; \
    case 8:  arr[8]  += (xx); break; case 9:  arr[9]  += (xx); break; \
    case 10: arr[10] += (xx); break; case 11: arr[11] += (xx); break; \
    case 12: arr[12] += (xx); break; case 13: arr[13] += (xx); break; \
    case 14: arr[14] += (xx); break; case 15: arr[15] += (xx); break; \
    case 16: arr[16] += (xx); break; case 17: arr[17] += (xx); break; \
    case 18: arr[18] += (xx); break; case 19: arr[19] += (xx); break; \
    case 20: arr[20] += (xx); break; default: break; } } while (0)

// ---------------- kernel 1: pseudo labels + per-class counts ----------------
__global__ __launch_bounds__(256) void k_labels(const int* __restrict__ labels,
                                                const float* __restrict__ outputs_old,
                                                int* __restrict__ lab,
                                                float* __restrict__ gcnt)
{
    __shared__ float cnt[NUMC];
    if (threadIdx.x < NUMC) cnt[threadIdx.x] = 0.f;
    __syncthreads();

    int p = blockIdx.x * 256 + threadIdx.x;
    int b = p >> 14;
    int rem = p & 16383;
    int h = rem >> 7;
    int w = rem & 127;
    int ld = labels[b * 262144 + (h * 4) * 512 + (w * 4)];
    int out = ld;
    if (ld == 0) {
        const float* oo = outputs_old + (size_t)b * BSTR + (size_t)(h * 4) * 512 + (w * 4);
        float v0 = oo[0];
        float best = (v0 < 0.7f) ? 0.0f : v0;
        int bi = 0;
        #pragma unroll
        for (int c = 1; c < 16; ++c) {
            float v = oo[(size_t)c * 262144];
            v = (v < 0.7f) ? 0.0f : v;
            if (v > best) { best = v; bi = c; }   // strict > == first-occurrence argmax
        }
        out = bi;
    }
    lab[p] = out;
    unsafeAtomicAdd(&cnt[out], 1.0f);
    __syncthreads();
    if (threadIdx.x < NUMC) unsafeAtomicAdd(&gcnt[threadIdx.x], cnt[threadIdx.x]);
}

// ---------------- kernel 2: sums of squares, pure streaming ----------------
// grid 1024: pxg (128) x chgrp (8). Thread owns 1 pixel-quad x 32 channels.
// Wave load = 64 lanes x float4 = 1KB contiguous. No LDS, no barriers.
__global__ __launch_bounds__(256) void k_norms(const float* __restrict__ fa,
                                               const float* __restrict__ fo,
                                               float* __restrict__ ssqA,
                                               float* __restrict__ ssqO)
{
    int pxg = blockIdx.x >> 3;
    int chg = blockIdx.x & 7;
    int p   = (pxg * 256 + threadIdx.x) * 4;     // global pixel (quad base)
    int img = p >> 14;
    int hw  = p & 16383;
    const float* pA = fa + (size_t)img * BSTR + (size_t)(chg * 32) * HW + hw;
    const float* pO = fo + (size_t)img * BSTR + (size_t)(chg * 32) * HW + hw;
    float4 sa = {0.f,0.f,0.f,0.f}, so = {0.f,0.f,0.f,0.f};
    #pragma unroll 8
    for (int c = 0; c < 32; ++c) {
        float4 a = *(const float4*)(pA + (size_t)c * HW);
        float4 o = *(const float4*)(pO + (size_t)c * HW);
        sa.x += a.x*a.x; sa.y += a.y*a.y; sa.z += a.z*a.z; sa.w += a.w*a.w;
        so.x += o.x*o.x; so.y += o.y*o.y; so.z += o.z*o.z; so.w += o.w*o.w;
    }
    unsafeAtomicAdd(&ssqA[p+0], sa.x);  unsafeAtomicAdd(&ssqA[p+1], sa.y);
    unsafeAtomicAdd(&ssqA[p+2], sa.z);  unsafeAtomicAdd(&ssqA[p+3], sa.w);
    unsafeAtomicAdd(&ssqO[p+0], so.x);  unsafeAtomicAdd(&ssqO[p+1], so.y);
    unsafeAtomicAdd(&ssqO[p+2], so.z);  unsafeAtomicAdd(&ssqO[p+3], so.w);
}

// ---------------- kernel 3: fused per-class accumulate (A + O) ----------------
// 1024 blocks x 256 thr; block owns 128 px (4 chunks of 32). Thread = channel.
// Class sums in REGISTERS (block-uniform label -> scalar switch). LDS = one
// 32px x 257 transpose tile. Double-buffered float4 prefetch.
__global__ __launch_bounds__(256, 3) void k_accum(const float* __restrict__ fa,
                                                  const float* __restrict__ fo,
                                                  const int* __restrict__ lab,
                                                  const float* __restrict__ ssqA,
                                                  const float* __restrict__ ssqO,
                                                  float* __restrict__ partA,
                                                  float* __restrict__ partO)
{
    __shared__ float tile[32 * TPAD];
    float aA[NUMC], aO[NUMC];
    #pragma unroll
    for (int k = 0; k < NUMC; ++k) { aA[k] = 0.f; aO[k] = 0.f; }

    const int t  = threadIdx.x;
    const int sc = t >> 3;            // staging channel base (0..31)
    const int e  = (t & 7) * 4;       // staging pixel offset (0,4..28)
    const int pbase = blockIdx.x * 128;
    const int img   = pbase >> 14;
    const int hw0   = pbase & 16383;
    const float* gA = fa + (size_t)img * BSTR + hw0;
    const float* gO = fo + (size_t)img * BSTR + hw0;

    float4 va[8], vo[8];
    #pragma unroll
    for (int i = 0; i < 8; ++i)
        va[i] = *(const float4*)(gA + (size_t)(sc + 32 * i) * HW + e);

    for (int ch = 0; ch < 4; ++ch) {
        const int pb  = pbase + ch * 32;
        const int off = ch * 32;

        __syncthreads();                        // tile free
        #pragma unroll
        for (int i = 0; i < 8; ++i) {           // stage A (transpose)
            int c = sc + 32 * i;
            tile[(e+0)*TPAD + c] = va[i].x;
            tile[(e+1)*TPAD + c] = va[i].y;
            tile[(e+2)*TPAD + c] = va[i].z;
            tile[(e+3)*TPAD + c] = va[i].w;
        }
        #pragma unroll
        for (int i = 0; i < 8; ++i)             // prefetch O (hides under acc-A)
            vo[i] = *(const float4*)(gO + (size_t)(sc + 32 * i) * HW + off + e);
        __syncthreads();                        // A tile ready

        #pragma unroll
        for (int j = 0; j < 32; ++j) {          // acc A: label is block-uniform
            int   k  = lab[pb + j];
            float iv = 1.0f / fmaxf(sqrtf(ssqA[pb + j]), 1e-12f);
            float x  = tile[j * TPAD + t] * iv;
            ACC21(aA, k, x);
        }
        __syncthreads();                        // A tile consumed

        #pragma unroll
        for (int i = 0; i < 8; ++i) {           // stage O
            int c = sc + 32 * i;
            tile[(e+0)*TPAD + c] = vo[i].x;
            tile[(e+1)*TPAD + c] = vo[i].y;
            tile[(e+2)*TPAD + c] = vo[i].z;
            tile[(e+3)*TPAD + c] = vo[i].w;
        }
        if (ch < 3) {
            #pragma unroll
            for (int i = 0; i < 8; ++i)         // prefetch next A
                va[i] = *(const float4*)(gA + (size_t)(sc + 32 * i) * HW + off + 32 + e);
        }
        __syncthreads();                        // O tile ready

        #pragma unroll
        for (int j = 0; j < 32; ++j) {
            int   k  = lab[pb + j];
            float iv = 1.0f / fmaxf(sqrtf(ssqO[pb + j]), 1e-12f);
            float x  = tile[j * TPAD + t] * iv;
            ACC21(aO, k, x);
        }
    }

    const int rep = blockIdx.x & (NREP - 1);
    #pragma unroll
    for (int k = 0; k < NUMC; ++k) {
        unsafeAtomicAdd(&partA[rep * KC + k * 256 + t], aA[k]);
        unsafeAtomicAdd(&partO[rep * KC + k * 256 + t], aO[k]);
    }
}

// ---------------- kernel 4: finalize (tiny) ----------------
__global__ __launch_bounds__(256) void k_final(const float* __restrict__ partA,
                                               const float* __restrict__ partO,
                                               const float* __restrict__ gcnt,
                                               float* __restrict__ out)
{
    __shared__ float anc[NUMC * 260];
    __shared__ float con[NUMC * 260];
    __shared__ float adc[NUMC * 44];
    __shared__ float cntS[NUMC];
    __shared__ float rowloss[NUMC];
    __shared__ float rowvalid[NUMC];

    if (threadIdx.x < NUMC) cntS[threadIdx.x] = gcnt[threadIdx.x];
    __syncthreads();
    for (int i = threadIdx.x; i < KC; i += 256) {
        float sA = 0.f, sO = 0.f;
        #pragma unroll
        for (int r = 0; r < NREP; ++r) { sA += partA[r * KC + i]; sO += partO[r * KC + i]; }
        int k = i >> 8, c = i & 255;
        float cn = cntS[k];
        bool pr = cn > 0.f;
        float d = pr ? cn : 1.f;
        anc[k * 260 + c] = pr ? sA / d : 0.f;
        con[k * 260 + c] = pr ? sO / d : 0.f;
    }
    __syncthreads();
    // adc[k][j] = dot(anc_k, contrast_j)/T,  contrast = [anc; con]
    for (int pair = threadIdx.x; pair < NUMC * 2 * NUMC; pair += 256) {
        int k = pair / (2 * NUMC);
        int j = pair % (2 * NUMC);
        const float* ar = anc + k * 260;
        const float* br = (j < NUMC) ? (anc + j * 260) : (con + (j - NUMC) * 260);
        float s = 0.f;
        for (int c = 0; c < CCH; c += 4) {
            float4 a4 = *(const float4*)(ar + c);
            float4 b4 = *(const float4*)(br + c);
            s += a4.x * b4.x + a4.y * b4.y + a4.z * b4.z + a4.w * b4.w;
        }
        adc[k * 44 + j] = s / 0.07f;
    }
    __syncthreads();
    if (threadIdx.x < NUMC) {
        int k = threadIdx.x;
        bool pr = cntS[k] > 0.f;
        float neg = 0.f;       // faithful to source — negatives use UNshifted logits
        float mx = -1e30f;
        for (int j = 0; j < 2 * NUMC; ++j) {
            int cj = (j < NUMC) ? j : (j - NUMC);
            bool cp = cntS[cj] > 0.f;
            float v = adc[k * 44 + j];
            if (cp) {
                if (v > mx) mx = v;
                if (j != k && j != NUMC + k) neg += expf(v);
            }
        }
        float sh = adc[k * 44 + NUMC + k] - mx;
        float rl = -(sh - logf(expf(sh) + neg));
        rowloss[k] = pr ? rl : 0.f;
        rowvalid[k] = pr ? 1.f : 0.f;
    }
    __syncthreads();
    if (threadIdx.x == 0) {
        float s = 0.f, v = 0.f;
        for (int kk = 0; kk < NUMC; ++kk) { s += rowloss[kk]; v += rowvalid[kk]; }
        out[0] = s / fmaxf(v, 1.f);
    }
}

// ---------------- launch ----------------
extern "C" void kernel_launch(void* const* d_in, const int* in_sizes, int n_in,
                              void* d_out, int out_size, void* d_ws, size_t ws_size,
                              hipStream_t stream) {
    const int*   labels      = (const int*)  d_in[0];
    const float* feats_old   = (const float*)d_in[1];
    const float* feats       = (const float*)d_in[2];
    const float* outputs_old = (const float*)d_in[3];
    // d_in[4] (outputs) and d_in[5] (prototypes) are unused by the reference math.

    float* ws    = (float*)d_ws;
    int*   lab   = (int*)ws;                   // [131072]
    float* ssqA  = ws + 131072;                // [131072]
    float* ssqO  = ws + 262144;                // [131072]
    float* partA = ws + 393216;                // [16*5376]
    float* partO = partA + NREP * KC;          // [16*5376]
    float* gcnt  = partO + NREP * KC;          // [21]

    // zero ssqA..gcnt (contiguous)
    hipMemsetAsync(ssqA, 0, (size_t)(2 * NPIX + 2 * NREP * KC + NUMC) * sizeof(float), stream);

    k_labels<<<NPIX / 256, 256, 0, stream>>>(labels, outputs_old, lab, gcnt);
    k_norms <<<1024, 256, 0, stream>>>(feats, feats_old, ssqA, ssqO);
    k_accum <<<1024, 256, 0, stream>>>(feats, feats_old, lab, ssqA, ssqO, partA, partO);
    k_final <<<1, 256, 0, stream>>>(partA, partO, gcnt, (float*)d_out);
}

// Round 6
// 117.129 us; speedup vs baseline: 3.7913x; 3.4078x over previous
//
#include <hip/hip_runtime.h>
#include <math.h>

#define NPIX   131072      // 8*128*128
#define CCH    256
#define HW     16384       // 128*128
#define BSTR   4194304     // 256*16384 (features b-stride)
#define NUMC   21
#define KC     5376        // 21*256
#define NREP   16
#define TSTR   20          // tile row stride (floats): 16B-aligned rows, banks spread 8-wise

// ---------------- kernel 1: pseudo labels + per-class counts ----------------
__global__ __launch_bounds__(256) void k_labels(const int* __restrict__ labels,
                                                const float* __restrict__ outputs_old,
                                                int* __restrict__ lab,
                                                float* __restrict__ gcnt)
{
    __shared__ float cnt[NUMC];
    if (threadIdx.x < NUMC) cnt[threadIdx.x] = 0.f;
    __syncthreads();

    int p = blockIdx.x * 256 + threadIdx.x;
    int b = p >> 14;
    int rem = p & 16383;
    int h = rem >> 7;
    int w = rem & 127;
    int ld = labels[b * 262144 + (h * 4) * 512 + (w * 4)];
    int out = ld;
    if (ld == 0) {
        const float* oo = outputs_old + (size_t)b * BSTR + (size_t)(h * 4) * 512 + (w * 4);
        float v0 = oo[0];
        float best = (v0 < 0.7f) ? 0.0f : v0;
        int bi = 0;
        #pragma unroll
        for (int c = 1; c < 16; ++c) {
            float v = oo[(size_t)c * 262144];
            v = (v < 0.7f) ? 0.0f : v;
            if (v > best) { best = v; bi = c; }   // strict > == first-occurrence argmax
        }
        out = bi;
    }
    lab[p] = out;
    unsafeAtomicAdd(&cnt[out], 1.0f);
    __syncthreads();
    if (threadIdx.x < NUMC) unsafeAtomicAdd(&gcnt[threadIdx.x], cnt[threadIdx.x]);
}

// ---------------- kernel 2: fused norm + per-class accumulate ----------------
// grid 1024: block (pb, tensor-parity). Block owns 256 px, 16 phases x 16 px.
// Thread <-> channel for accumulation: acc[k*256+t] rmw'd ONLY by thread t ->
// plain ds_read/fma/ds_write, no atomics, no switch. ssq computed from staged
// data (norm pass fused away). invn broadcast via lane shuffle.
__global__ __launch_bounds__(256, 3) void k_accum(const float* __restrict__ fa,
                                                  const float* __restrict__ fo,
                                                  const int* __restrict__ lab,
                                                  float* __restrict__ partA,
                                                  float* __restrict__ partO)
{
    __shared__ float acc[KC];            // 21.0 KB
    __shared__ float tile[CCH * TSTR];   // 20.0 KB  [ch][16px] stride 20
    __shared__ float ssqPart[64];        // [wave][16px]
    __shared__ int   labS[256];

    const int t = threadIdx.x;
    const int w = t >> 6, l = t & 63;
    const int isO = blockIdx.x & 1;
    const float* src = isO ? fo : fa;
    float* part = isO ? partO : partA;

    const int pbase = (blockIdx.x >> 1) * 256;
    const int img   = pbase >> 14;
    const int hw0   = pbase & 16383;
    const float* g  = src + (size_t)img * BSTR + hw0;

    const int chb = t >> 2;              // channel base (0..63), +64*i
    const int gq  = (t & 3) * 4;         // pixel offset within phase (0,4,8,12)

    for (int i = t; i < KC; i += 256) acc[i] = 0.f;
    labS[t] = lab[pbase + t];

#define ISSUE(buf, ph) do { \
    _Pragma("unroll") \
    for (int i_ = 0; i_ < 4; ++i_) \
        buf[i_] = *(const float4*)(g + (size_t)(chb + 64 * i_) * HW + (ph) * 16 + gq); \
    } while (0)

    // stage tile + compute ssq partials (16-lane shuffle reduce over channels)
#define STAGE(buf) do { \
    float4 s4 = {0.f, 0.f, 0.f, 0.f}; \
    _Pragma("unroll") \
    for (int i_ = 0; i_ < 4; ++i_) { \
        float4 v_ = buf[i_]; \
        *(float4*)&tile[(chb + 64 * i_) * TSTR + gq] = v_; \
        s4.x += v_.x * v_.x; s4.y += v_.y * v_.y; \
        s4.z += v_.z * v_.z; s4.w += v_.w * v_.w; \
    } \
    _Pragma("unroll") \
    for (int off_ = 4; off_ < 64; off_ <<= 1) { \
        s4.x += __shfl_xor(s4.x, off_, 64); \
        s4.y += __shfl_xor(s4.y, off_, 64); \
        s4.z += __shfl_xor(s4.z, off_, 64); \
        s4.w += __shfl_xor(s4.w, off_, 64); \
    } \
    if (l < 4) *(float4*)&ssqPart[w * 16 + l * 4] = s4; \
    } while (0)

#define UPD(kk, xx, jj) do { \
    float iv_ = __shfl(invn_l, (jj), 64); \
    acc[(kk) * 256 + t] += (xx) * iv_; \
    } while (0)

#define CONSUME(ph) do { \
    float invn_l = 0.f; \
    if (l < 16) { \
        float ss_ = ssqPart[l] + ssqPart[16 + l] + ssqPart[32 + l] + ssqPart[48 + l]; \
        invn_l = 1.0f / fmaxf(sqrtf(ss_), 1e-12f); \
    } \
    int4 lb0 = *(const int4*)&labS[(ph) * 16 + 0]; \
    int4 lb1 = *(const int4*)&labS[(ph) * 16 + 4]; \
    int4 lb2 = *(const int4*)&labS[(ph) * 16 + 8]; \
    int4 lb3 = *(const int4*)&labS[(ph) * 16 + 12]; \
    float4 r0 = *(const float4*)&tile[t * TSTR + 0]; \
    float4 r1 = *(const float4*)&tile[t * TSTR + 4]; \
    float4 r2 = *(const float4*)&tile[t * TSTR + 8]; \
    float4 r3 = *(const float4*)&tile[t * TSTR + 12]; \
    UPD(lb0.x, r0.x,  0); UPD(lb0.y, r0.y,  1); UPD(lb0.z, r0.z,  2); UPD(lb0.w, r0.w,  3); \
    UPD(lb1.x, r1.x,  4); UPD(lb1.y, r1.y,  5); UPD(lb1.z, r1.z,  6); UPD(lb1.w, r1.w,  7); \
    UPD(lb2.x, r2.x,  8); UPD(lb2.y, r2.y,  9); UPD(lb2.z, r2.z, 10); UPD(lb2.w, r2.w, 11); \
    UPD(lb3.x, r3.x, 12); UPD(lb3.y, r3.y, 13); UPD(lb3.z, r3.z, 14); UPD(lb3.w, r3.w, 15); \
    } while (0)

    float4 va[4], vb[4];
    ISSUE(va, 0);
    __syncthreads();                      // labS + acc zero visible

    for (int it = 0; it < 8; ++it) {
        const int ph = it * 2;
        STAGE(va);
        ISSUE(vb, ph + 1);                // in flight under consume
        __syncthreads();                  // tile + ssqPart ready
        CONSUME(ph);
        __syncthreads();                  // tile free
        STAGE(vb);
        if (it < 7) ISSUE(va, ph + 2);
        __syncthreads();
        CONSUME(ph + 1);
        if (it < 7) __syncthreads();      // tile free for next iter's STAGE
    }

    __syncthreads();                      // acc complete across all waves
    const int rep = (blockIdx.x >> 1) & (NREP - 1);
    #pragma unroll
    for (int k = 0; k < NUMC; ++k)
        unsafeAtomicAdd(&part[rep * KC + k * 256 + t], acc[k * 256 + t]);

#undef ISSUE
#undef STAGE
#undef UPD
#undef CONSUME
}

// ---------------- kernel 3: finalize (tiny) ----------------
__global__ __launch_bounds__(256) void k_final(const float* __restrict__ partA,
                                               const float* __restrict__ partO,
                                               const float* __restrict__ gcnt,
                                               float* __restrict__ out)
{
    __shared__ float anc[NUMC * 260];
    __shared__ float con[NUMC * 260];
    __shared__ float adc[NUMC * 44];
    __shared__ float cntS[NUMC];
    __shared__ float rowloss[NUMC];
    __shared__ float rowvalid[NUMC];

    if (threadIdx.x < NUMC) cntS[threadIdx.x] = gcnt[threadIdx.x];
    __syncthreads();
    for (int i = threadIdx.x; i < KC; i += 256) {
        float sA = 0.f, sO = 0.f;
        #pragma unroll
        for (int r = 0; r < NREP; ++r) { sA += partA[r * KC + i]; sO += partO[r * KC + i]; }
        int k = i >> 8, c = i & 255;
        float cn = cntS[k];
        bool pr = cn > 0.f;
        float d = pr ? cn : 1.f;
        anc[k * 260 + c] = pr ? sA / d : 0.f;
        con[k * 260 + c] = pr ? sO / d : 0.f;
    }
    __syncthreads();
    // adc[k][j] = dot(anc_k, contrast_j)/T,  contrast = [anc; con]
    for (int pair = threadIdx.x; pair < NUMC * 2 * NUMC; pair += 256) {
        int k = pair / (2 * NUMC);
        int j = pair % (2 * NUMC);
        const float* ar = anc + k * 260;
        const float* br = (j < NUMC) ? (anc + j * 260) : (con + (j - NUMC) * 260);
        float s = 0.f;
        for (int c = 0; c < CCH; c += 4) {
            float4 a4 = *(const float4*)(ar + c);
            float4 b4 = *(const float4*)(br + c);
            s += a4.x * b4.x + a4.y * b4.y + a4.z * b4.z + a4.w * b4.w;
        }
        adc[k * 44 + j] = s / 0.07f;
    }
    __syncthreads();
    if (threadIdx.x < NUMC) {
        int k = threadIdx.x;
        bool pr = cntS[k] > 0.f;
        float neg = 0.f;       // faithful to source — negatives use UNshifted logits
        float mx = -1e30f;
        for (int j = 0; j < 2 * NUMC; ++j) {
            int cj = (j < NUMC) ? j : (j - NUMC);
            bool cp = cntS[cj] > 0.f;
            float v = adc[k * 44 + j];
            if (cp) {
                if (v > mx) mx = v;
                if (j != k && j != NUMC + k) neg += expf(v);
            }
        }
        float sh = adc[k * 44 + NUMC + k] - mx;
        float rl = -(sh - logf(expf(sh) + neg));
        rowloss[k] = pr ? rl : 0.f;
        rowvalid[k] = pr ? 1.f : 0.f;
    }
    __syncthreads();
    if (threadIdx.x == 0) {
        float s = 0.f, v = 0.f;
        for (int kk = 0; kk < NUMC; ++kk) { s += rowloss[kk]; v += rowvalid[kk]; }
        out[0] = s / fmaxf(v, 1.f);
    }
}

// ---------------- launch ----------------
extern "C" void kernel_launch(void* const* d_in, const int* in_sizes, int n_in,
                              void* d_out, int out_size, void* d_ws, size_t ws_size,
                              hipStream_t stream) {
    const int*   labels      = (const int*)  d_in[0];
    const float* feats_old   = (const float*)d_in[1];
    const float* feats       = (const float*)d_in[2];
    const float* outputs_old = (const float*)d_in[3];
    // d_in[4] (outputs) and d_in[5] (prototypes) are unused by the reference math.

    float* ws    = (float*)d_ws;
    int*   lab   = (int*)ws;                   // [131072]
    float* partA = ws + 131072;                // [16*5376]
    float* partO = partA + NREP * KC;          // [16*5376]
    float* gcnt  = partO + NREP * KC;          // [21]

    hipMemsetAsync(partA, 0, (size_t)(2 * NREP * KC + NUMC) * sizeof(float), stream);

    k_labels<<<NPIX / 256, 256, 0, stream>>>(labels, outputs_old, lab, gcnt);
    k_accum <<<1024, 256, 0, stream>>>(feats, feats_old, lab, partA, partO);
    k_final <<<1, 256, 0, stream>>>(partA, partO, gcnt, (float*)d_out);
}

// Round 7
// 100.514 us; speedup vs baseline: 4.4180x; 1.1653x over previous
//
#include <hip/hip_runtime.h>
#include <math.h>

#define NPIX   131072      // 8*128*128
#define CCH    256
#define HW     16384       // 128*128
#define BSTR   4194304     // 256*16384 (features b-stride)
#define NUMC   21
#define KC     5376        // 21*256
#define NREP   16

typedef __attribute__((ext_vector_type(8))) short bf16x8;   // 8 bf16 (4 VGPRs)
typedef __attribute__((ext_vector_type(4))) float f32x4;

static __device__ __forceinline__ uint f2bf(float x) {      // f32 -> bf16 bits, RTNE
    uint u = __builtin_bit_cast(uint, x);
    return (u + 0x7FFFu + ((u >> 16) & 1u)) >> 16;
}
static __device__ __forceinline__ uint oh(int lbl, int cls) { // onehot as bf16 bits
    return (lbl == cls) ? 0x3F80u : 0u;
}

// ---------------- kernel 1: pseudo labels + per-class counts ----------------
__global__ __launch_bounds__(256) void k_labels(const int* __restrict__ labels,
                                                const float* __restrict__ outputs_old,
                                                int* __restrict__ lab,
                                                float* __restrict__ gcnt)
{
    __shared__ float cnt[NUMC];
    if (threadIdx.x < NUMC) cnt[threadIdx.x] = 0.f;
    __syncthreads();

    int p = blockIdx.x * 256 + threadIdx.x;
    int b = p >> 14;
    int rem = p & 16383;
    int h = rem >> 7;
    int w = rem & 127;
    int ld = labels[b * 262144 + (h * 4) * 512 + (w * 4)];
    int out = ld;
    if (ld == 0) {
        const float* oo = outputs_old + (size_t)b * BSTR + (size_t)(h * 4) * 512 + (w * 4);
        float v0 = oo[0];
        float best = (v0 < 0.7f) ? 0.0f : v0;
        int bi = 0;
        #pragma unroll
        for (int c = 1; c < 16; ++c) {
            float v = oo[(size_t)c * 262144];
            v = (v < 0.7f) ? 0.0f : v;
            if (v > best) { best = v; bi = c; }   // strict > == first-occurrence argmax
        }
        out = bi;
    }
    lab[p] = out;
    unsafeAtomicAdd(&cnt[out], 1.0f);
    __syncthreads();
    if (threadIdx.x < NUMC) unsafeAtomicAdd(&gcnt[threadIdx.x], cnt[threadIdx.x]);
}

// ---------------- kernel 2: fused norm + MFMA per-class sums ----------------
// grid 1024 = 512 px-blocks x 2 tensors. Block: 256 px, 8 phases x 32 px.
// Per phase: load f32 (coalesced 128B rows) -> ssq shuffle-reduce -> normalize,
// cvt bf16, stage [32px x 256ch] tile -> MFMA: D[cls][ch] += onehot[cls][px] x fan[px][ch].
// Class sums accumulate in AGPRs; zero per-element LDS rmw, zero switch.
__global__ __launch_bounds__(256, 4) void k_msum(const float* __restrict__ fa,
                                                 const float* __restrict__ fo,
                                                 const int* __restrict__ lab,
                                                 float* __restrict__ partA,
                                                 float* __restrict__ partO)
{
    __shared__ ushort tile[32 * 256];   // bf16, elem (p,ch) at ((p>>3)*256+ch)*8 + (p&7)
    __shared__ float4 ssqP4[32];        // [wave*8 + quad]
    __shared__ int    labS[256];

    const int t = threadIdx.x;
    const int w = t >> 6, l = t & 63;
    const int isO = blockIdx.x & 1;
    const float* __restrict__ src = isO ? fo : fa;
    float* part = isO ? partO : partA;

    const int pbase = (blockIdx.x >> 1) * 256;
    const int img   = pbase >> 14;
    const int hw0   = pbase & 16383;
    const float* g  = src + (size_t)img * BSTR + hw0;

    labS[t] = lab[pbase + t];

    const int chb = w * 8 + (l >> 3);   // channel base, +32*i (i=0..7)
    const int pq  = l & 7;              // pixel-quad within phase (px = pq*4 + r)

    f32x4 acc[2][4];                    // [cls-tile][ch-tile-local] -> AGPRs
    #pragma unroll
    for (int m = 0; m < 2; ++m)
        #pragma unroll
        for (int n = 0; n < 4; ++n)
            acc[m][n] = (f32x4){0.f, 0.f, 0.f, 0.f};

    float4 v[8];
    #pragma unroll
    for (int i = 0; i < 8; ++i)         // prologue: phase-0 loads
        v[i] = *(const float4*)(g + (size_t)(chb + 32 * i) * HW + pq * 4);

    for (int ph = 0; ph < 8; ++ph) {
        // --- ssq: per-thread partial over its 8 channels, 4 px ---
        float4 s = {0.f, 0.f, 0.f, 0.f};
        #pragma unroll
        for (int i = 0; i < 8; ++i) {
            s.x += v[i].x * v[i].x;  s.y += v[i].y * v[i].y;
            s.z += v[i].z * v[i].z;  s.w += v[i].w * v[i].w;
        }
        #pragma unroll
        for (int off = 8; off < 64; off <<= 1) {    // reduce over lane bits 3..5
            s.x += __shfl_xor(s.x, off, 64);
            s.y += __shfl_xor(s.y, off, 64);
            s.z += __shfl_xor(s.z, off, 64);
            s.w += __shfl_xor(s.w, off, 64);
        }
        if (l < 8) ssqP4[w * 8 + l] = make_float4(s.x, s.y, s.z, s.w);
        __syncthreads();                            // b1: ssqP ready; prev MFMA tile reads done
        float4 q0 = ssqP4[pq],      q1 = ssqP4[8 + pq];
        float4 q2 = ssqP4[16 + pq], q3 = ssqP4[24 + pq];
        float4 inv;
        inv.x = 1.0f / fmaxf(sqrtf(q0.x + q1.x + q2.x + q3.x), 1e-12f);
        inv.y = 1.0f / fmaxf(sqrtf(q0.y + q1.y + q2.y + q3.y), 1e-12f);
        inv.z = 1.0f / fmaxf(sqrtf(q0.z + q1.z + q2.z + q3.z), 1e-12f);
        inv.w = 1.0f / fmaxf(sqrtf(q0.w + q1.w + q2.w + q3.w), 1e-12f);

        // --- normalize + cvt bf16 + stage tile ---
        #pragma unroll
        for (int i = 0; i < 8; ++i) {
            uint lo = f2bf(v[i].x * inv.x) | (f2bf(v[i].y * inv.y) << 16);
            uint hi = f2bf(v[i].z * inv.z) | (f2bf(v[i].w * inv.w) << 16);
            int ch = chb + 32 * i;
            *(uint2*)&tile[(((pq >> 1) * 256 + ch) << 3) + ((pq & 1) << 2)] =
                make_uint2(lo, hi);
        }
        if (ph < 7) {                               // prefetch next phase (flies over MFMA)
            #pragma unroll
            for (int i = 0; i < 8; ++i)
                v[i] = *(const float4*)(g + (size_t)(chb + 32 * i) * HW + (ph + 1) * 32 + pq * 4);
        }
        __syncthreads();                            // b2: tile ready

        // --- A-frags (onehot from labels, registers only) ---
        const int base = ph * 32 + ((l >> 4) << 3); // px k-group of this lane
        int4 la = *(const int4*)&labS[base];
        int4 lb = *(const int4*)&labS[base + 4];
        const int cls0 = l & 15, cls1 = 16 + (l & 15);
        uint4 u0, u1;
        u0.x = oh(la.x, cls0) | (oh(la.y, cls0) << 16);
        u0.y = oh(la.z, cls0) | (oh(la.w, cls0) << 16);
        u0.z = oh(lb.x, cls0) | (oh(lb.y, cls0) << 16);
        u0.w = oh(lb.z, cls0) | (oh(lb.w, cls0) << 16);
        u1.x = oh(la.x, cls1) | (oh(la.y, cls1) << 16);
        u1.y = oh(la.z, cls1) | (oh(la.w, cls1) << 16);
        u1.z = oh(lb.x, cls1) | (oh(lb.y, cls1) << 16);
        u1.w = oh(lb.z, cls1) | (oh(lb.w, cls1) << 16);
        bf16x8 A0 = __builtin_bit_cast(bf16x8, u0);
        bf16x8 A1 = __builtin_bit_cast(bf16x8, u1);

        // --- MFMAs: wave owns ch-tiles w*4..w*4+3 ---
        #pragma unroll
        for (int n = 0; n < 4; ++n) {
            const int ct = w * 4 + n;
            const bf16x8 B = *(const bf16x8*)&tile[((l >> 4) * 256 + ct * 16 + (l & 15)) << 3];
            acc[0][n] = __builtin_amdgcn_mfma_f32_16x16x32_bf16(A0, B, acc[0][n], 0, 0, 0);
            acc[1][n] = __builtin_amdgcn_mfma_f32_16x16x32_bf16(A1, B, acc[1][n], 0, 0, 0);
        }
    }

    // --- epilogue: D[cls][ch] -> replica atomics (col=lane&15, row=(lane>>4)*4+r) ---
    const int rep = (blockIdx.x >> 1) & (NREP - 1);
    #pragma unroll
    for (int m = 0; m < 2; ++m)
        #pragma unroll
        for (int n = 0; n < 4; ++n) {
            const int col = (w * 4 + n) * 16 + (l & 15);
            #pragma unroll
            for (int r = 0; r < 4; ++r) {
                const int row = m * 16 + (l >> 4) * 4 + r;
                if (row < NUMC)
                    unsafeAtomicAdd(&part[rep * KC + row * 256 + col], acc[m][n][r]);
            }
        }
}

// ---------------- kernel 3: finalize (tiny) ----------------
__global__ __launch_bounds__(256) void k_final(const float* __restrict__ partA,
                                               const float* __restrict__ partO,
                                               const float* __restrict__ gcnt,
                                               float* __restrict__ out)
{
    __shared__ float anc[NUMC * 260];
    __shared__ float con[NUMC * 260];
    __shared__ float adc[NUMC * 44];
    __shared__ float cntS[NUMC];
    __shared__ float rowloss[NUMC];
    __shared__ float rowvalid[NUMC];

    if (threadIdx.x < NUMC) cntS[threadIdx.x] = gcnt[threadIdx.x];
    __syncthreads();
    for (int i = threadIdx.x; i < KC; i += 256) {
        float sA = 0.f, sO = 0.f;
        #pragma unroll
        for (int r = 0; r < NREP; ++r) { sA += partA[r * KC + i]; sO += partO[r * KC + i]; }
        int k = i >> 8, c = i & 255;
        float cn = cntS[k];
        bool pr = cn > 0.f;
        float d = pr ? cn : 1.f;
        anc[k * 260 + c] = pr ? sA / d : 0.f;
        con[k * 260 + c] = pr ? sO / d : 0.f;
    }
    __syncthreads();
    // adc[k][j] = dot(anc_k, contrast_j)/T,  contrast = [anc; con]
    for (int pair = threadIdx.x; pair < NUMC * 2 * NUMC; pair += 256) {
        int k = pair / (2 * NUMC);
        int j = pair % (2 * NUMC);
        const float* ar = anc + k * 260;
        const float* br = (j < NUMC) ? (anc + j * 260) : (con + (j - NUMC) * 260);
        float s = 0.f;
        for (int c = 0; c < CCH; c += 4) {
            float4 a4 = *(const float4*)(ar + c);
            float4 b4 = *(const float4*)(br + c);
            s += a4.x * b4.x + a4.y * b4.y + a4.z * b4.z + a4.w * b4.w;
        }
        adc[k * 44 + j] = s / 0.07f;
    }
    __syncthreads();
    if (threadIdx.x < NUMC) {
        int k = threadIdx.x;
        bool pr = cntS[k] > 0.f;
        float neg = 0.f;       // faithful to source — negatives use UNshifted logits
        float mx = -1e30f;
        for (int j = 0; j < 2 * NUMC; ++j) {
            int cj = (j < NUMC) ? j : (j - NUMC);
            bool cp = cntS[cj] > 0.f;
            float v = adc[k * 44 + j];
            if (cp) {
                if (v > mx) mx = v;
                if (j != k && j != NUMC + k) neg += expf(v);
            }
        }
        float sh = adc[k * 44 + NUMC + k] - mx;
        float rl = -(sh - logf(expf(sh) + neg));
        rowloss[k] = pr ? rl : 0.f;
        rowvalid[k] = pr ? 1.f : 0.f;
    }
    __syncthreads();
    if (threadIdx.x == 0) {
        float s = 0.f, v = 0.f;
        for (int kk = 0; kk < NUMC; ++kk) { s += rowloss[kk]; v += rowvalid[kk]; }
        out[0] = s / fmaxf(v, 1.f);
    }
}

// ---------------- launch ----------------
extern "C" void kernel_launch(void* const* d_in, const int* in_sizes, int n_in,
                              void* d_out, int out_size, void* d_ws, size_t ws_size,
                              hipStream_t stream) {
    const int*   labels      = (const int*)  d_in[0];
    const float* feats_old   = (const float*)d_in[1];
    const float* feats       = (const float*)d_in[2];
    const float* outputs_old = (const float*)d_in[3];
    // d_in[4] (outputs) and d_in[5] (prototypes) are unused by the reference math.

    float* ws    = (float*)d_ws;
    int*   lab   = (int*)ws;                   // [131072]
    float* partA = ws + 131072;                // [16*5376]
    float* partO = partA + NREP * KC;          // [16*5376]
    float* gcnt  = partO + NREP * KC;          // [21]

    hipMemsetAsync(partA, 0, (size_t)(2 * NREP * KC + NUMC) * sizeof(float), stream);

    k_labels<<<NPIX / 256, 256, 0, stream>>>(labels, outputs_old, lab, gcnt);
    k_msum  <<<1024, 256, 0, stream>>>(feats, feats_old, lab, partA, partO);
    k_final <<<1, 256, 0, stream>>>(partA, partO, gcnt, (float*)d_out);
}